// Round 12
// baseline (163.306 us; speedup 1.0000x reference)
//
#include <hip/hip_runtime.h>
#include <hip/hip_bf16.h>

#define BATCH 32
#define SEQ   2048
#define DIM   64
#define KT    64
#define NIT   (SEQ / KT)   // 32
#define QTB   64           // q-rows per block (256 threads, 4 waves, 4 blocks/CU)

typedef __attribute__((ext_vector_type(8))) short bf16x8;
typedef __attribute__((ext_vector_type(4))) short bf16x4;
typedef __attribute__((ext_vector_type(4))) float fx4;
typedef __attribute__((ext_vector_type(4))) int   ix4;

static __device__ __forceinline__ short f2bf(float f) {
    __bf16 h = (__bf16)f;
    return *(short*)&h;
}
static __device__ __forceinline__ bf16x8 cvt8(fx4 a, fx4 b) {
    bf16x8 s;
    s[0] = f2bf(a[0]); s[1] = f2bf(a[1]); s[2] = f2bf(a[2]); s[3] = f2bf(a[3]);
    s[4] = f2bf(b[0]); s[5] = f2bf(b[1]); s[6] = f2bf(b[2]); s[7] = f2bf(b[3]);
    return s;
}
static __device__ __forceinline__ bf16x4 cvt4(float a, float b, float c, float d) {
    bf16x4 s; s[0] = f2bf(a); s[1] = f2bf(b); s[2] = f2bf(c); s[3] = f2bf(d);
    return s;
}

// exp2 trick: Q pre-scaled by log2(e)/sqrt(D)
#define QSCALE (0.125f * 1.44269504088896f)

// 256-thread block = 4 waves = 64 q-rows, 4 blocks/CU (4 independent barrier
// groups per CU -> phase-decorrelated pipe overlap; K/V duplication L2-served).
// KT=64, round-10 iteration structure (best known).
// LDS (32 KB/block, double-buffered), layouts validated rounds 3-10:
//   K buf b: [b*8192,+8192): [64 keys][128B], byte(col c)=2c ^ ((key&7)<<4)
//   V buf b: [16384+b*8192,+8192): two 32-key halves (hb*4096), pair-rows [32][128B]:
//            d->(pr=d>>1,u=d&1), in-half key k5 -> byte u*64 + 16*((k5>>2)&3)
//            + 8*(k5>>4) + 2*(k5&3), all ^ ((pr&7)<<4)
// Mask (round-8 optimal shape): loader lane (rg=lane>>4, cq=lane&15); instr s
//   covers row 4s+rg x 256B; ballot-transpose to consumer lanes; ~1-iter flight.
// Staging: single regset, issue at iter top, ds_write at bottom (~2.5us flight).
//   K: 4x dwordx4 + 2x b128.  V: 4 row-wise dwordx4 + in-reg transpose + 4x b64.
__global__ __launch_bounds__(256, 4)
void attn_fwd(const float* __restrict__ Qg, const float* __restrict__ Kg,
              const float* __restrict__ Vg, const int* __restrict__ Mg,
              float* __restrict__ Og)
{
    __shared__ __align__(16) char smem[32768];

    // XCD swizzle: grid 1024 -> XCD x owns bids [x*128,(x+1)*128) = 4 batches
    const int bid   = (int)((blockIdx.x & 7) * 128 + (blockIdx.x >> 3));
    const int b     = bid >> 5;
    const int qbase = (bid & 31) * QTB;
    const int tid   = threadIdx.x;
    const int wave  = tid >> 6;
    const int lane  = tid & 63;
    const int l15   = lane & 15;
    const int g     = lane >> 4;

    // Q fragment (B-operand of swapped QK^T), pre-scaled
    const int qrow_g = qbase + wave * 16 + l15;
    const float* qrow = Qg + ((size_t)(b * SEQ + qrow_g) * DIM);
    bf16x8 qf[2];
#pragma unroll
    for (int h = 0; h < 2; ++h) {
        fx4 a = *(const fx4*)(qrow + h * 32 + g * 8);
        fx4 c = *(const fx4*)(qrow + h * 32 + g * 8 + 4);
        a *= QSCALE; c *= QSCALE;
        qf[h] = cvt8(a, c);
    }

    // mask loader + consumer constants (validated round 8)
    const int rg = lane >> 4, cq = lane & 15;
    const int* mload = Mg + ((size_t)(b * SEQ + qbase + wave * 16 + rg) * SEQ) + cq * 4;
    const bool srb0 = (l15 & 4) != 0;
    const bool srb1 = (l15 & 8) != 0;
    const int  mbase = (l15 & 3) * 16 + g;

    // K staging: thread (kr=tid>>2 in [0,64), kc16=tid&3): 4 fx4 loads, 2 b128 writes
    const int kr = tid >> 2, kc16 = tid & 3;
    const float* ksrc = Kg + ((size_t)(b * SEQ + kr) * DIM) + kc16 * 16;
    const int ksw2 = (kr & 7) * 16;
    const int kwofs0 = kr * 128 + ((kc16 * 32)      ^ ksw2);
    const int kwofs1 = kr * 128 + ((kc16 * 32 + 16) ^ ksw2);

    // V staging: thread (v4=(tid&15)*4, jgy=tid>>4 in [0,16)): keys 4jgy..+4,
    // cols v4..+4; 4 fx4 ROW loads; 4 b64 transposed writes
    const int v4 = (tid & 15) * 4, jgy = tid >> 4;
    const float* vsrc = Vg + ((size_t)(b * SEQ + 4 * jgy) * DIM) + v4;
    const int vhb = (jgy >> 3) * 4096;
    const int vcm = 16 * (jgy & 3) + 8 * ((jgy >> 2) & 1);
    const int prA = v4 >> 1, prB = prA + 1;
    int vw[4];
    vw[0] = vhb + prA * 128 + ((vcm)      ^ ((prA & 7) * 16));
    vw[1] = vhb + prA * 128 + ((64 + vcm) ^ ((prA & 7) * 16));
    vw[2] = vhb + prB * 128 + ((vcm)      ^ ((prB & 7) * 16));
    vw[3] = vhb + prB * 128 + ((64 + vcm) ^ ((prB & 7) * 16));

    // fragment read offsets (layouts validated rounds 3-10)
    const int ksw  = (l15 & 7) * 16;
    const int koh0 = l15 * 128 + ((16 * g)      ^ ksw);
    const int koh1 = l15 * 128 + ((16 * g + 64) ^ ksw);
    const int vrof = (l15 >> 1) * 128 + (((l15 & 1) * 64 + 16 * g) ^ ((l15 >> 1) * 16));

    fx4 acc[4] = {};
    float lsum = 0.f;

    fx4 kReg[4];
    fx4 vReg[4];
    ix4 m[4];

    // ---- prologue: tile 0 -> LDS buf0; masks tile 0 -> m ----
    {
#pragma unroll
        for (int j = 0; j < 4; ++j) kReg[j] = *(const fx4*)(ksrc + 4 * j);
#pragma unroll
        for (int i = 0; i < 4; ++i) vReg[i] = *(const fx4*)(vsrc + (size_t)i * DIM);
#pragma unroll
        for (int s = 0; s < 4; ++s)
            m[s] = __builtin_nontemporal_load((const ix4*)(mload + (size_t)4 * s * SEQ));
        *(bf16x8*)(smem + kwofs0) = cvt8(kReg[0], kReg[1]);
        *(bf16x8*)(smem + kwofs1) = cvt8(kReg[2], kReg[3]);
#pragma unroll
        for (int dd = 0; dd < 4; ++dd)
            *(bf16x4*)(smem + 16384 + vw[dd]) =
                cvt4(vReg[0][dd], vReg[1][dd], vReg[2][dd], vReg[3][dd]);
    }
    asm volatile("s_waitcnt lgkmcnt(0)" ::: "memory");
    __builtin_amdgcn_s_barrier();
    __builtin_amdgcn_sched_barrier(0);

#pragma unroll 2
    for (int kt = 0; kt < NIT; ++kt) {
        const int cur = kt & 1, nxt = cur ^ 1;
        const int kb1 = ((kt + 1) & (NIT - 1)) * KT;   // wraps at end: dead loads

        // A. issue K/V loads for tile t+1 (ds_write at H: ~full-compute flight)
#pragma unroll
        for (int j = 0; j < 4; ++j)
            kReg[j] = *(const fx4*)(ksrc + (size_t)kb1 * DIM + 4 * j);
#pragma unroll
        for (int i = 0; i < 4; ++i)
            vReg[i] = *(const fx4*)(vsrc + (size_t)(kb1 + i) * DIM);

        // B. ballot-transpose mask tile t (loads ~1 iter old; the wait leaves
        //    this iter's younger K/V loads in flight)
        unsigned long long bal[4][4];
#pragma unroll
        for (int s = 0; s < 4; ++s)
#pragma unroll
            for (int i = 0; i < 4; ++i)
                bal[s][i] = __ballot(m[s][i] != 0);

        // C. reissue the SAME mask regs for tile t+1 (WAR; ~1-iter flight)
#pragma unroll
        for (int s = 0; s < 4; ++s)
            m[s] = __builtin_nontemporal_load((const ix4*)(mload + (size_t)4 * s * SEQ + kb1));

        // D. QK^T: 4 key sub-tiles x 2 d-halves on buf[cur]
        const char* kB_ = smem + cur * 8192;
        fx4 sc[4];
#pragma unroll
        for (int s = 0; s < 4; ++s) {
            bf16x8 kf0 = *(const bf16x8*)(kB_ + s * 2048 + koh0);
            bf16x8 kf1 = *(const bf16x8*)(kB_ + s * 2048 + koh1);
            fx4 t = {};
            t = __builtin_amdgcn_mfma_f32_16x16x32_bf16(kf0, qf[0], t, 0, 0, 0);
            t = __builtin_amdgcn_mfma_f32_16x16x32_bf16(kf1, qf[1], t, 0, 0, 0);
            sc[s] = t;
        }

        // E. masked exp from ballot bits
        float p[16];
#pragma unroll
        for (int i = 0; i < 4; ++i) {
            unsigned long long W = srb1 ? (srb0 ? bal[3][i] : bal[2][i])
                                        : (srb0 ? bal[1][i] : bal[0][i]);
            unsigned bits = (unsigned)(W >> mbase);
            p[0 + i]  = (bits & 1u)         ? 0.f : __builtin_amdgcn_exp2f(sc[0][i]);
            p[4 + i]  = ((bits >> 4) & 1u)  ? 0.f : __builtin_amdgcn_exp2f(sc[1][i]);
            p[8 + i]  = ((bits >> 8) & 1u)  ? 0.f : __builtin_amdgcn_exp2f(sc[2][i]);
            p[12 + i] = ((bits >> 12) & 1u) ? 0.f : __builtin_amdgcn_exp2f(sc[3][i]);
        }

        lsum += (((p[0] + p[1]) + (p[2] + p[3])) + ((p[4] + p[5]) + (p[6] + p[7])))
              + (((p[8] + p[9]) + (p[10] + p[11])) + ((p[12] + p[13]) + (p[14] + p[15])));

        bf16x8 pf0, pf1;
#pragma unroll
        for (int j = 0; j < 8; ++j) { pf0[j] = f2bf(p[j]); pf1[j] = f2bf(p[8 + j]); }

        // F. PV: two 32-key halves x 4 d sub-tiles
        const char* vB_ = smem + 16384 + cur * 8192 + vrof;
#pragma unroll
        for (int dsub = 0; dsub < 4; ++dsub) {
            bf16x8 vf = *(const bf16x8*)(vB_ + dsub * 1024);
            acc[dsub] = __builtin_amdgcn_mfma_f32_16x16x32_bf16(vf, pf0, acc[dsub], 0, 0, 0);
        }
#pragma unroll
        for (int dsub = 0; dsub < 4; ++dsub) {
            bf16x8 vf = *(const bf16x8*)(vB_ + 4096 + dsub * 1024);
            acc[dsub] = __builtin_amdgcn_mfma_f32_16x16x32_bf16(vf, pf1, acc[dsub], 0, 0, 0);
        }

        // H. ds_write tile t+1 into buf[nxt] (A-loads fully covered; the dep-wait
        //    leaves the younger C mask loads in flight)
        *(bf16x8*)(smem + nxt * 8192 + kwofs0) = cvt8(kReg[0], kReg[1]);
        *(bf16x8*)(smem + nxt * 8192 + kwofs1) = cvt8(kReg[2], kReg[3]);
#pragma unroll
        for (int dd = 0; dd < 4; ++dd)
            *(bf16x4*)(smem + 16384 + nxt * 8192 + vw[dd]) =
                cvt4(vReg[0][dd], vReg[1][dd], vReg[2][dd], vReg[3][dd]);

        // I. raw barrier: own-wave LDS drain only — no vmcnt drain
        asm volatile("s_waitcnt lgkmcnt(0)" ::: "memory");
        __builtin_amdgcn_s_barrier();
        __builtin_amdgcn_sched_barrier(0);
    }

    // ---- epilogue: reduce l over 4 g-replicas, normalize, store ----
    lsum += __shfl_xor(lsum, 16);
    lsum += __shfl_xor(lsum, 32);
    const float inv = lsum > 0.f ? 1.0f / lsum : 0.f;   // fully-masked row -> 0

    float* obase = Og + ((size_t)(b * SEQ + qrow_g) * DIM) + 4 * g;
#pragma unroll
    for (int dsub = 0; dsub < 4; ++dsub) {
        fx4 o = acc[dsub] * inv;
        __builtin_nontemporal_store(o, (fx4*)(obase + dsub * 16));
    }
}

extern "C" void kernel_launch(void* const* d_in, const int* in_sizes, int n_in,
                              void* d_out, int out_size, void* d_ws, size_t ws_size,
                              hipStream_t stream) {
    const float* Q = (const float*)d_in[0];
    const float* K = (const float*)d_in[1];
    const float* V = (const float*)d_in[2];
    const int*   M = (const int*)d_in[3];
    float*       O = (float*)d_out;
    dim3 grid(BATCH * (SEQ / QTB));
    attn_fwd<<<grid, 256, 0, stream>>>(Q, K, V, M, O);
}

// Round 13
// 118.783 us; speedup vs baseline: 1.3748x; 1.3748x over previous
//
#include <hip/hip_runtime.h>
#include <hip/hip_bf16.h>

#define BATCH 32
#define SEQ   2048
#define DIM   64
#define KT    64
#define NIT   (SEQ / KT)   // 32
#define QTB   128          // q-rows per block (512 threads, 8 waves, 2 blocks/CU)

typedef __attribute__((ext_vector_type(8))) short bf16x8;
typedef __attribute__((ext_vector_type(4))) short bf16x4;
typedef __attribute__((ext_vector_type(4))) float fx4;
typedef __attribute__((ext_vector_type(4))) int   ix4;

static __device__ __forceinline__ short f2bf(float f) {
    __bf16 h = (__bf16)f;
    return *(short*)&h;
}
static __device__ __forceinline__ bf16x8 cvt8(fx4 a, fx4 b) {
    bf16x8 s;
    s[0] = f2bf(a[0]); s[1] = f2bf(a[1]); s[2] = f2bf(a[2]); s[3] = f2bf(a[3]);
    s[4] = f2bf(b[0]); s[5] = f2bf(b[1]); s[6] = f2bf(b[2]); s[7] = f2bf(b[3]);
    return s;
}
static __device__ __forceinline__ bf16x4 cvt4(float a, float b, float c, float d) {
    bf16x4 s; s[0] = f2bf(a); s[1] = f2bf(b); s[2] = f2bf(c); s[3] = f2bf(d);
    return s;
}

// exp2 trick: Q pre-scaled by log2(e)/sqrt(D)
#define QSCALE (0.125f * 1.44269504088896f)

// ROUND-10 CONFIG (measured 119.0 us) — best known; reverted after r11/r12
// regressions falsified the remaining axes (barrier granularity, blocks/CU).
// 512-thread block = 8 waves = 128 q-rows, 2 blocks/CU.
// Mask: round-8 optimal shape: per wave, instruction s covers rows 4s+rg
//   (rg=lane>>4) x 256B contiguous; ballot-transpose to consumer lanes.
// LDS (32 KB/block, double-buffered), layouts validated rounds 3-10:
//   K buf b: [b*8192,+8192): [64 keys][128B], byte(col c)=2c ^ ((key&7)<<4)
//   V buf b: [16384+b*8192,+8192): two 32-key halves (kh*4096), pair-rows [32][128B]:
//            d->(pr=d>>1,u=d&1), key k5 -> byte u*64+16*((k5>>2)&3)+8*(k5>>4)+2*(k5&3),
//            all ^ ((pr&7)<<4)
// Pipeline: iter t: K/V tile t+2 -> regs[nxt]; QK on buf[cur]; ballot+consume mask t,
// reissue mask regs for t+1 (WAR, ~1-iter flight); PV; ds_write tile t+1 from
// regs[cur]; lgkm-only barrier (in-flight vmem survives).
__global__ __launch_bounds__(512, 4)
void attn_fwd(const float* __restrict__ Qg, const float* __restrict__ Kg,
              const float* __restrict__ Vg, const int* __restrict__ Mg,
              float* __restrict__ Og)
{
    __shared__ __align__(16) char smem[32768];

    // XCD swizzle: grid 512 -> XCD x owns bids [x*64,(x+1)*64) = 4 batches
    const int bid   = (int)((blockIdx.x & 7) * 64 + (blockIdx.x >> 3));
    const int b     = bid >> 4;
    const int qbase = (bid & 15) * QTB;
    const int tid   = threadIdx.x;
    const int wave  = tid >> 6;
    const int lane  = tid & 63;
    const int l15   = lane & 15;
    const int g     = lane >> 4;

    // Q fragment (B-operand of swapped QK^T), pre-scaled
    const int qrow_g = qbase + wave * 16 + l15;
    const float* qrow = Qg + ((size_t)(b * SEQ + qrow_g) * DIM);
    bf16x8 qf[2];
#pragma unroll
    for (int h = 0; h < 2; ++h) {
        fx4 a = *(const fx4*)(qrow + h * 32 + g * 8);
        fx4 c = *(const fx4*)(qrow + h * 32 + g * 8 + 4);
        a *= QSCALE; c *= QSCALE;
        qf[h] = cvt8(a, c);
    }

    // mask loader (round-8 burst shape): lane (rg=lane>>4, cq=lane&15); instr s
    // covers row 4s+rg of the wave's 16 rows, cols cq*4..+4 (4 rows x 256B/instr)
    const int rg = lane >> 4, cq = lane & 15;
    const int* mload = Mg + ((size_t)(b * SEQ + qbase + wave * 16 + rg) * SEQ) + cq * 4;

    // mask consumer constants (validated round 8)
    const bool srb0 = (l15 & 4) != 0;
    const bool srb1 = (l15 & 8) != 0;
    const int  mbase = (l15 & 3) * 16 + g;

    // K staging: thread (kr=tid>>3 in [0,64), kc8=tid&7): 2x fx4 load, 1 b128 write
    const int kr = tid >> 3, kc8 = tid & 7;
    const float* ksrc = Kg + ((size_t)(b * SEQ + kr) * DIM) + kc8 * 8;
    const int kwofs = kr * 128 + ((kc8 * 16) ^ ((kr & 7) * 16));

    // V staging: thread (vd=tid&63, jg8=tid>>6 in [0,8)): keys jg8*8..+8, col vd;
    // 8 scalar loads (d-coalesced), 2 b64 writes
    const int vd = tid & 63, jg8 = tid >> 6;
    const float* vsrc = Vg + ((size_t)(b * SEQ + jg8 * 8) * DIM) + vd;
    const int vpr = vd >> 1, vu = vd & 1, q3 = jg8 & 3, vh = jg8 >> 2;
    const int vsw = (vpr & 7) * 16;
    const int vwofs0 = 16384 + vh * 4096 + vpr * 128 +
                       (((vu * 64) + 16 * ((2 * q3) & 3)     + 8 * (q3 >> 1)) ^ vsw);
    const int vwofs1 = 16384 + vh * 4096 + vpr * 128 +
                       (((vu * 64) + 16 * ((2 * q3 + 1) & 3) + 8 * (q3 >> 1)) ^ vsw);

    // fragment read offsets (layouts validated rounds 3-8)
    const int ksw  = (l15 & 7) * 16;
    const int koh0 = l15 * 128 + ((16 * g)      ^ ksw);
    const int koh1 = l15 * 128 + ((16 * g + 64) ^ ksw);
    const int vrof = (l15 >> 1) * 128 + (((l15 & 1) * 64 + 16 * g) ^ ((l15 >> 1) * 16));

    fx4 acc[4] = {};
    float lsum = 0.f;

    fx4   kReg[2][2];
    float vReg[2][8];
    ix4   m[4];

    // ---- prologue: tile 0 -> LDS, tile 1 -> regs, mask tile 0 -> regs ----
    {
        fx4 kA = *(const fx4*)(ksrc);
        fx4 kB = *(const fx4*)(ksrc + 4);
        float v0[8];
#pragma unroll
        for (int i = 0; i < 8; ++i) v0[i] = vsrc[(size_t)i * DIM];
        kReg[0][0] = *(const fx4*)(ksrc + (size_t)KT * DIM);
        kReg[0][1] = *(const fx4*)(ksrc + (size_t)KT * DIM + 4);
#pragma unroll
        for (int i = 0; i < 8; ++i) vReg[0][i] = vsrc[(size_t)(KT + i) * DIM];
#pragma unroll
        for (int s = 0; s < 4; ++s)
            m[s] = __builtin_nontemporal_load((const ix4*)(mload + (size_t)4 * s * SEQ));
        *(bf16x8*)(smem + kwofs) = cvt8(kA, kB);
        *(bf16x4*)(smem + vwofs0) = cvt4(v0[0], v0[1], v0[2], v0[3]);
        *(bf16x4*)(smem + vwofs1) = cvt4(v0[4], v0[5], v0[6], v0[7]);
    }
    asm volatile("s_waitcnt lgkmcnt(0)" ::: "memory");
    __builtin_amdgcn_s_barrier();
    __builtin_amdgcn_sched_barrier(0);

#pragma unroll 2
    for (int kt = 0; kt < NIT; ++kt) {
        const int cur = kt & 1, nxt = cur ^ 1;
        const int kb2 = ((kt + 2) & (NIT - 1)) * KT;   // wraps at end: dead loads
        const int kb1 = ((kt + 1) & (NIT - 1)) * KT;

        // 1. issue K/V loads for tile t+2 into regset[nxt]
        kReg[nxt][0] = *(const fx4*)(ksrc + (size_t)kb2 * DIM);
        kReg[nxt][1] = *(const fx4*)(ksrc + (size_t)kb2 * DIM + 4);
#pragma unroll
        for (int i = 0; i < 8; ++i) vReg[nxt][i] = vsrc[(size_t)(kb2 + i) * DIM];

        // 2. QK^T: 4 key sub-tiles x 2 d-halves on buf[cur]
        const char* kB_ = smem + cur * 8192;
        fx4 sc[4];
#pragma unroll
        for (int s = 0; s < 4; ++s) {
            bf16x8 kf0 = *(const bf16x8*)(kB_ + s * 2048 + koh0);
            bf16x8 kf1 = *(const bf16x8*)(kB_ + s * 2048 + koh1);
            fx4 t = {};
            t = __builtin_amdgcn_mfma_f32_16x16x32_bf16(kf0, qf[0], t, 0, 0, 0);
            t = __builtin_amdgcn_mfma_f32_16x16x32_bf16(kf1, qf[1], t, 0, 0, 0);
            sc[s] = t;
        }

        // 3a. ballot-transpose mask tile t (loads ~1 iter old; vmcnt wait leaves
        //     this iter's younger K/V loads in flight)
        unsigned long long bal[4][4];
#pragma unroll
        for (int s = 0; s < 4; ++s)
#pragma unroll
            for (int i = 0; i < 4; ++i)
                bal[s][i] = __ballot(m[s][i] != 0);

        // 3b. reissue the SAME mask regs for tile t+1 (WAR; ~1-iter flight)
#pragma unroll
        for (int s = 0; s < 4; ++s)
            m[s] = __builtin_nontemporal_load((const ix4*)(mload + (size_t)4 * s * SEQ + kb1));

        // 3c. masked exp from ballot bits
        float p[16];
#pragma unroll
        for (int i = 0; i < 4; ++i) {
            unsigned long long W = srb1 ? (srb0 ? bal[3][i] : bal[2][i])
                                        : (srb0 ? bal[1][i] : bal[0][i]);
            unsigned bits = (unsigned)(W >> mbase);
            p[0 + i]  = (bits & 1u)         ? 0.f : __builtin_amdgcn_exp2f(sc[0][i]);
            p[4 + i]  = ((bits >> 4) & 1u)  ? 0.f : __builtin_amdgcn_exp2f(sc[1][i]);
            p[8 + i]  = ((bits >> 8) & 1u)  ? 0.f : __builtin_amdgcn_exp2f(sc[2][i]);
            p[12 + i] = ((bits >> 12) & 1u) ? 0.f : __builtin_amdgcn_exp2f(sc[3][i]);
        }

        lsum += (((p[0] + p[1]) + (p[2] + p[3])) + ((p[4] + p[5]) + (p[6] + p[7])))
              + (((p[8] + p[9]) + (p[10] + p[11])) + ((p[12] + p[13]) + (p[14] + p[15])));

        bf16x8 pf0, pf1;
#pragma unroll
        for (int j = 0; j < 8; ++j) { pf0[j] = f2bf(p[j]); pf1[j] = f2bf(p[8 + j]); }

        // 4. PV: two 32-key halves x 4 d sub-tiles
        const char* vB_ = smem + 16384 + cur * 8192 + vrof;
#pragma unroll
        for (int dsub = 0; dsub < 4; ++dsub) {
            bf16x8 vf = *(const bf16x8*)(vB_ + dsub * 1024);
            acc[dsub] = __builtin_amdgcn_mfma_f32_16x16x32_bf16(vf, pf0, acc[dsub], 0, 0, 0);
        }
#pragma unroll
        for (int dsub = 0; dsub < 4; ++dsub) {
            bf16x8 vf = *(const bf16x8*)(vB_ + 4096 + dsub * 1024);
            acc[dsub] = __builtin_amdgcn_mfma_f32_16x16x32_bf16(vf, pf1, acc[dsub], 0, 0, 0);
        }

        // 5. ds_write tile t+1 from regset[cur] (loads 1 iter old: latency covered)
        *(bf16x8*)(smem + nxt * 8192 + kwofs) = cvt8(kReg[cur][0], kReg[cur][1]);
        *(bf16x4*)(smem + nxt * 8192 + vwofs0) =
            cvt4(vReg[cur][0], vReg[cur][1], vReg[cur][2], vReg[cur][3]);
        *(bf16x4*)(smem + nxt * 8192 + vwofs1) =
            cvt4(vReg[cur][4], vReg[cur][5], vReg[cur][6], vReg[cur][7]);

        // 6. raw barrier: own-wave LDS drain only — no vmcnt drain
        asm volatile("s_waitcnt lgkmcnt(0)" ::: "memory");
        __builtin_amdgcn_s_barrier();
        __builtin_amdgcn_sched_barrier(0);
    }

    // ---- epilogue: reduce l over 4 g-replicas, normalize, store ----
    lsum += __shfl_xor(lsum, 16);
    lsum += __shfl_xor(lsum, 32);
    const float inv = lsum > 0.f ? 1.0f / lsum : 0.f;   // fully-masked row -> 0

    float* obase = Og + ((size_t)(b * SEQ + qrow_g) * DIM) + 4 * g;
#pragma unroll
    for (int dsub = 0; dsub < 4; ++dsub) {
        fx4 o = acc[dsub] * inv;
        __builtin_nontemporal_store(o, (fx4*)(obase + dsub * 16));
    }
}

extern "C" void kernel_launch(void* const* d_in, const int* in_sizes, int n_in,
                              void* d_out, int out_size, void* d_ws, size_t ws_size,
                              hipStream_t stream) {
    const float* Q = (const float*)d_in[0];
    const float* K = (const float*)d_in[1];
    const float* V = (const float*)d_in[2];
    const int*   M = (const int*)d_in[3];
    float*       O = (float*)d_out;
    dim3 grid(BATCH * (SEQ / QTB));
    attn_fwd<<<grid, 512, 0, stream>>>(Q, K, V, M, O);
}